// Round 3
// baseline (210.576 us; speedup 1.0000x reference)
//
#include <hip/hip_runtime.h>
#include <hip/hip_bf16.h>

// Problem constants: D=512, H=8, L=4, NE=8, B=32, S=512, VOCAB=64
// Algebraic reduction: cross-attention has Sk=1 -> softmax over a length-1
// axis == 1.0 -> its output at every query position is v = ctx@cWv + cbv
// (head split/concat is identity), so
//   last = ((context @ ctxW + ctxb) @ cWv + cbv) @ cWo + cbo
// The embedding + 4-layer transformer stack (and cWq/cWk) is dead code.
//
// Dtypes (established R0-R2):
//   - inputs fp32 (bf16 reinterpret gave NaN -> fp32 mantissa bits)
//   - output fp32 (packed-bf16 write gave finite-garbage 0.47 > max|ref|)

#define DD 512
#define BB 32
#define OW 64

__global__ __launch_bounds__(256) void hivemind_tail(
    const float* __restrict__ ctxin,   // context_batch (B,2) fp32
    const int*   __restrict__ sid,     // specialist_ids (B,) int32
    const float* __restrict__ ctxW,    // (2,D)
    const float* __restrict__ ctxb,    // (D,)
    const float* __restrict__ cWv,     // (D,D)
    const float* __restrict__ cbv,     // (D,)
    const float* __restrict__ cWo,     // (D,D)
    const float* __restrict__ cbo,     // (D,)
    const float* __restrict__ spWp,    // (NE,D,64)
    const float* __restrict__ spbp,    // (NE,64)
    const float* __restrict__ spWa,    // (NE,D,64)
    const float* __restrict__ spba,    // (NE,64)
    float*       __restrict__ out)     // pred (B,64) then act (B,64), fp32
{
    __shared__ float ctx[DD];
    __shared__ float v[DD];
    __shared__ float lastv[DD];

    const int b = blockIdx.x;
    const int t = threadIdx.x;

    const float c0 = ctxin[b * 2 + 0];
    const float c1 = ctxin[b * 2 + 1];

    // ctx = context @ ctxW + ctxb   (2 elements per thread, coalesced)
    for (int d = t; d < DD; d += 256) {
        ctx[d] = c0 * ctxW[d] + c1 * ctxW[DD + d] + ctxb[d];
    }
    __syncthreads();

    // v = ctx @ cWv + cbv ; thread t owns columns 2t, 2t+1 (float2 loads)
    {
        const int e = 2 * t;
        float a0 = 0.f, a1 = 0.f;
        #pragma unroll 8
        for (int d = 0; d < DD; ++d) {
            const float c = ctx[d];
            const float2 w = reinterpret_cast<const float2*>(cWv + (size_t)d * DD)[t];
            a0 += c * w.x;
            a1 += c * w.y;
        }
        v[e]     = a0 + cbv[e];
        v[e + 1] = a1 + cbv[e + 1];
    }
    __syncthreads();

    // last = v @ cWo + cbo
    {
        const int e = 2 * t;
        float a0 = 0.f, a1 = 0.f;
        #pragma unroll 8
        for (int d = 0; d < DD; ++d) {
            const float c = v[d];
            const float2 w = reinterpret_cast<const float2*>(cWo + (size_t)d * DD)[t];
            a0 += c * w.x;
            a1 += c * w.y;
        }
        lastv[e]     = a0 + cbo[e];
        lastv[e + 1] = a1 + cbo[e + 1];
    }
    __syncthreads();

    // pred / act heads: threads 0..63 -> pred, 64..127 -> act
    if (t < 128) {
        const int o = t & 63;
        const int s = sid[b];
        const float* W    = (t < 64) ? spWp : spWa;
        const float* bias = (t < 64) ? spbp : spba;
        const float* w = W + (size_t)s * DD * OW + o;
        float a = 0.f;
        #pragma unroll 8
        for (int d = 0; d < DD; ++d) {
            a += lastv[d] * w[(size_t)d * OW];
        }
        a += bias[s * OW + o];
        const int idx = ((t < 64) ? 0 : BB * OW) + b * OW + o;
        out[idx] = a;
    }
}

extern "C" void kernel_launch(void* const* d_in, const int* in_sizes, int n_in,
                              void* d_out, int out_size, void* d_ws, size_t ws_size,
                              hipStream_t stream) {
    // setup_inputs order:
    // 0 x_batch, 1 context_batch, 2 specialist_ids, 3 emb, 4 Wq, 5 bq, 6 Wk, 7 bk,
    // 8 Wv, 9 bv, 10 Wo, 11 bo, 12 ln1_s, 13 ln1_b, 14 ln2_s, 15 ln2_b,
    // 16 W1, 17 b1, 18 W2, 19 b2, 20 ctxW, 21 ctxb, 22 cWq, 23 cbq, 24 cWk, 25 cbk,
    // 26 cWv, 27 cbv, 28 cWo, 29 cbo, 30 spWp, 31 spbp, 32 spWa, 33 spba
    const float* ctxin = (const float*)d_in[1];
    const int*   sid   = (const int*)d_in[2];
    const float* ctxW  = (const float*)d_in[20];
    const float* ctxb  = (const float*)d_in[21];
    const float* cWv   = (const float*)d_in[26];
    const float* cbv   = (const float*)d_in[27];
    const float* cWo   = (const float*)d_in[28];
    const float* cbo   = (const float*)d_in[29];
    const float* spWp  = (const float*)d_in[30];
    const float* spbp  = (const float*)d_in[31];
    const float* spWa  = (const float*)d_in[32];
    const float* spba  = (const float*)d_in[33];
    float* out = (float*)d_out;

    hivemind_tail<<<dim3(BB), dim3(256), 0, stream>>>(
        ctxin, sid, ctxW, ctxb, cWv, cbv, cWo, cbo,
        spWp, spbp, spWa, spba, out);
}

// Round 4
// 153.627 us; speedup vs baseline: 1.3707x; 1.3707x over previous
//
#include <hip/hip_runtime.h>

// Problem: D=512, H=8, L=4, NE=8, B=32, S=512. fp32 in / fp32 out (est. R0-R3).
//
// Reduction chain (R3-verified, absmax 0.0):
//   cross-attn Sk=1 -> softmax==1 -> last[b] = ((ctx[b])@cWv+cbv)@cWo+cbo,
//   ctx[b] = c0[b]*ctxW[0] + c1[b]*ctxW[1] + ctxb.
// New (R4): batch factors out of every GEMV by linearity:
//   A_i = x_i@cWv (i=0,1,2; x={ctxW0,ctxW1,ctxb}), A2 += cbv
//   B_i = A_i@cWo, B2 += cbo
//   P_i[s,h] = B_i@spW[h][s], P2 += spb[h][s]
//   out[b,h,o] = c0[b]*P0 + c1[b]*P1 + P2   (s = sid[b])
// 9 batch-free GEMVs, 4.2 MB weights read once, ~6 MFLOP. 3 tiny kernels.

#define DD 512

// stage a 3-vector GEMV: dst[vec*512+c] = sum_d x_vec[d]*W[d][c]  (+bias2[c] for vec 2)
// grid 32 blocks x 256 thr; block = 16-column slice; thread = (col, 32-d group)
__global__ __launch_bounds__(256) void stage_gemv3(
    const float* __restrict__ x0, const float* __restrict__ x1,
    const float* __restrict__ x2,
    const float* __restrict__ W,      // (512,512) row-major
    const float* __restrict__ bias2,  // (512) added to vec 2
    float*       __restrict__ dst)    // (3,512)
{
    __shared__ float sx0[DD], sx1[DD], sx2[DD];
    __shared__ float red[16][16][3];  // [dgroup][col][vec]
    const int t = threadIdx.x;
    const int cbase = blockIdx.x * 16;

    for (int i = t; i < DD; i += 256) {
        sx0[i] = x0[i]; sx1[i] = x1[i]; sx2[i] = x2[i];
    }
    __syncthreads();

    const int c = t & 15, dg = t >> 4;        // 16 cols x 16 d-groups of 32
    const float* wp = W + (size_t)(dg * 32) * DD + cbase + c;
    float p0 = 0.f, p1 = 0.f, p2 = 0.f;
    #pragma unroll
    for (int j = 0; j < 32; ++j) {            // 32 loads fully in flight
        const float w = wp[(size_t)j * DD];
        const int d = dg * 32 + j;
        p0 += sx0[d] * w; p1 += sx1[d] * w; p2 += sx2[d] * w;
    }
    red[dg][c][0] = p0; red[dg][c][1] = p1; red[dg][c][2] = p2;
    __syncthreads();

    if (t < 48) {
        const int vec = t >> 4, cc = t & 15;
        float s = 0.f;
        #pragma unroll
        for (int g = 0; g < 16; ++g) s += red[g][cc][vec];
        if (vec == 2) s += bias2[cbase + cc];
        dst[vec * DD + cbase + cc] = s;
    }
}

// specialist heads + broadcast to batches.
// grid 16 blocks (s = blk&7, h = blk>>3) x 512 thr; thread = (o, 64-d group)
__global__ __launch_bounds__(512) void stage_heads(
    const float* __restrict__ Bv,     // (3,512) at ws B region
    const float* __restrict__ spWp, const float* __restrict__ spbp,
    const float* __restrict__ spWa, const float* __restrict__ spba,
    const float* __restrict__ ctxin,  // (32,2)
    const int*   __restrict__ sid,    // (32)
    float*       __restrict__ out)    // pred (32,64) then act (32,64)
{
    __shared__ float b0[DD], b1[DD], b2[DD];
    __shared__ float red[8][64][3];
    __shared__ float pv[3][64];
    __shared__ float sc0[32], sc1[32];
    __shared__ int   ssid[32];
    const int t = threadIdx.x;
    const int s = blockIdx.x & 7, h = blockIdx.x >> 3;

    for (int i = t; i < DD; i += 512) {
        b0[i] = Bv[i]; b1[i] = Bv[DD + i]; b2[i] = Bv[2 * DD + i];
    }
    if (t < 32) {
        ssid[t] = sid[t];
        sc0[t] = ctxin[2 * t];
        sc1[t] = ctxin[2 * t + 1];
    }
    __syncthreads();

    const float* W    = (h ? spWa : spWp) + (size_t)s * DD * 64;
    const float* bias = (h ? spba : spbp) + s * 64;
    const int o = t & 63, dg = t >> 6;        // 64 outs x 8 d-groups of 64
    const float* wp = W + (size_t)(dg * 64) * 64 + o;
    float p0 = 0.f, p1 = 0.f, p2 = 0.f;
    #pragma unroll
    for (int j = 0; j < 64; ++j) {            // coalesced 256B rows
        const float w = wp[(size_t)j * 64];
        const int d = dg * 64 + j;
        p0 += b0[d] * w; p1 += b1[d] * w; p2 += b2[d] * w;
    }
    red[dg][o][0] = p0; red[dg][o][1] = p1; red[dg][o][2] = p2;
    __syncthreads();

    if (t < 192) {
        const int vec = t >> 6, oo = t & 63;
        float acc = 0.f;
        #pragma unroll
        for (int g = 0; g < 8; ++g) acc += red[g][oo][vec];
        if (vec == 2) acc += bias[oo];
        pv[vec][oo] = acc;
    }
    __syncthreads();

    if (t < 64) {
        // every b with sid[b]==s belongs to exactly this block (per head h)
        for (int b = 0; b < 32; ++b) {
            if (ssid[b] == s) {
                out[h * 2048 + b * 64 + t] =
                    sc0[b] * pv[0][t] + sc1[b] * pv[1][t] + pv[2][t];
            }
        }
    }
}

extern "C" void kernel_launch(void* const* d_in, const int* in_sizes, int n_in,
                              void* d_out, int out_size, void* d_ws, size_t ws_size,
                              hipStream_t stream) {
    // 0 x_batch, 1 context_batch, 2 specialist_ids, 3 emb, 4-11 attn W/b,
    // 12-15 ln, 16-19 ffn, 20 ctxW, 21 ctxb, 22 cWq, 23 cbq, 24 cWk, 25 cbk,
    // 26 cWv, 27 cbv, 28 cWo, 29 cbo, 30 spWp, 31 spbp, 32 spWa, 33 spba
    const float* ctxin = (const float*)d_in[1];
    const int*   sid   = (const int*)d_in[2];
    const float* ctxW  = (const float*)d_in[20];
    const float* ctxb  = (const float*)d_in[21];
    const float* cWv   = (const float*)d_in[26];
    const float* cbv   = (const float*)d_in[27];
    const float* cWo   = (const float*)d_in[28];
    const float* cbo   = (const float*)d_in[29];
    const float* spWp  = (const float*)d_in[30];
    const float* spbp  = (const float*)d_in[31];
    const float* spWa  = (const float*)d_in[32];
    const float* spba  = (const float*)d_in[33];
    float* out = (float*)d_out;
    float* wsf = (float*)d_ws;
    float* wsA = wsf;          // A[3][512]
    float* wsB = wsf + 3 * DD; // B[3][512]

    // A_i = {ctxW0, ctxW1, ctxb} @ cWv   (A2 += cbv)
    stage_gemv3<<<dim3(32), dim3(256), 0, stream>>>(
        ctxW, ctxW + DD, ctxb, cWv, cbv, wsA);
    // B_i = A_i @ cWo                    (B2 += cbo)
    stage_gemv3<<<dim3(32), dim3(256), 0, stream>>>(
        wsA, wsA + DD, wsA + 2 * DD, cWo, cbo, wsB);
    // heads + batch broadcast
    stage_heads<<<dim3(16), dim3(512), 0, stream>>>(
        wsB, spWp, spbp, spWa, spba, ctxin, sid, out);
}